// Round 1
// baseline (4627.923 us; speedup 1.0000x reference)
//
#include <hip/hip_runtime.h>
#include <cstdint>

typedef float f4 __attribute__((ext_vector_type(4)));

#define BHTD 3145728    // B*H*T*D = 2*12*2048*64 floats
#define BTC  3145728    // B*T*C floats
#define NT   2048
#define NC   768

// ---------------------------------------------------------------------------
// Kernel 1: fused QKV projection for nominal + interval bounds.
//   nom = x @ W^T ; mid = m @ W^T ; rad = r @ |W|^T  (m=(xl+xu)/2, r=(xu-xl)/2)
//   lo = mid - rad ; hi = mid + rad
// Output scattered into [variant][part][B,H,T,D] layout in ws.
// Tile 64x64, K-step 16, 256 threads, 4x4 per thread, 3 acc chains.
// ---------------------------------------------------------------------------
__global__ __launch_bounds__(256) void qkv_proj(
    const float* __restrict__ x, const float* __restrict__ xl,
    const float* __restrict__ xu, const float* __restrict__ W,
    float* __restrict__ ws)
{
    __shared__ float Axs[16][68], Ams[16][68], Ars[16][68], Bws[16][68];
    const int j0 = blockIdx.x * 64;   // output col tile (0..2304)
    const int n0 = blockIdx.y * 64;   // row tile (0..4096)
    const int t  = threadIdx.x;
    const int lrow = t >> 2;          // 0..63
    const int lf4  = (t & 3) * 4;     // 0,4,8,12
    const int tx = t & 15, ty = t >> 4;

    float nom[4][4], mid[4][4], rad[4][4];
#pragma unroll
    for (int a = 0; a < 4; a++)
#pragma unroll
        for (int b = 0; b < 4; b++) { nom[a][b] = 0.f; mid[a][b] = 0.f; rad[a][b] = 0.f; }

    for (int k0 = 0; k0 < NC; k0 += 16) {
        const f4 vx = *(const f4*)&x [(size_t)(n0 + lrow) * NC + k0 + lf4];
        const f4 vl = *(const f4*)&xl[(size_t)(n0 + lrow) * NC + k0 + lf4];
        const f4 vu = *(const f4*)&xu[(size_t)(n0 + lrow) * NC + k0 + lf4];
        const f4 vw = *(const f4*)&W [(size_t)(j0 + lrow) * NC + k0 + lf4];
        __syncthreads();
#pragma unroll
        for (int q = 0; q < 4; q++) {
            Axs[lf4 + q][lrow] = vx[q];
            Ams[lf4 + q][lrow] = 0.5f * (vl[q] + vu[q]);
            Ars[lf4 + q][lrow] = 0.5f * (vu[q] - vl[q]);
            Bws[lf4 + q][lrow] = vw[q];
        }
        __syncthreads();
#pragma unroll
        for (int kk = 0; kk < 16; kk++) {
            const f4 ax = *(const f4*)&Axs[kk][ty * 4];
            const f4 am = *(const f4*)&Ams[kk][ty * 4];
            const f4 ar = *(const f4*)&Ars[kk][ty * 4];
            const f4 bw = *(const f4*)&Bws[kk][tx * 4];
#pragma unroll
            for (int rr = 0; rr < 4; rr++)
#pragma unroll
                for (int cc = 0; cc < 4; cc++) {
                    nom[rr][cc] = fmaf(ax[rr], bw[cc], nom[rr][cc]);
                    mid[rr][cc] = fmaf(am[rr], bw[cc], mid[rr][cc]);
                    rad[rr][cc] = fmaf(ar[rr], fabsf(bw[cc]), rad[rr][cc]);
                }
        }
    }
    // epilogue: scatter into [B,H,T,D] per variant/part. 64-wide j-tile stays
    // within one (part, head) since 64 | 768.
    const int p = j0 / NC;
    const int h = (j0 % NC) / 64;
    const int d = tx * 4;
#pragma unroll
    for (int rr = 0; rr < 4; rr++) {
        const int n  = n0 + ty * 4 + rr;
        const int b  = n >> 11, tt2 = n & 2047;
        const size_t base = ((size_t)(b * 12 + h) * NT + tt2) * 64 + d;
        f4 fn, flo, fhi;
#pragma unroll
        for (int cc = 0; cc < 4; cc++) {
            fn[cc]  = nom[rr][cc];
            flo[cc] = mid[rr][cc] - rad[rr][cc];
            fhi[cc] = mid[rr][cc] + rad[rr][cc];
        }
        *(f4*)&ws[(size_t)(0 * 3 + p) * BHTD + base] = fn;
        *(f4*)&ws[(size_t)(1 * 3 + p) * BHTD + base] = flo;
        *(f4*)&ws[(size_t)(2 * 3 + p) * BHTD + base] = fhi;
    }
}

// ---------------------------------------------------------------------------
// Kernel 2: flash attention, 5 score-variants per block:
//   sv0: (qn,kn)x{vn}          -> y
//   sv1..4: (q lo/hi, k lo/hi)x{vlo,vhi} -> min/max folded into registers
// Block = (bh, qtile of 32 rows), 256 threads: row r=t>>3 (32 rows),
// 8 D-cols per thread for PV, 4 score-cols per thread.
// ---------------------------------------------------------------------------
__global__ __launch_bounds__(256) void flash9(float* __restrict__ ws)
{
    const int qtile = (int)gridDim.x - 1 - (int)blockIdx.x;  // heavy blocks first
    const int bh = blockIdx.y;
    const int q0 = qtile * 32;
    const int t  = threadIdx.x;
    const int r  = t >> 3;           // 0..31 (row in tile)
    const int c4 = (t & 7) * 4;      // score col group
    const int c8 = (t & 7) * 8;      // PV / load col group

    __shared__ float Qs[32][68];
    __shared__ float Ks[64][36];     // transposed: Ks[d][kcol]
    __shared__ float Vs[2][32][68];
    __shared__ float Ps[32][36];

    const size_t hb = (size_t)bh * NT * 64;
    float* ybuf = ws + (size_t)9 * BHTD;
    const float NEG_INF = -__builtin_inff();

    float olo[8], ohi[8];
#pragma unroll
    for (int i = 0; i < 8; i++) { olo[i] = 0.f; ohi[i] = 0.f; }

    for (int sv = 0; sv < 5; ++sv) {
        const int qvi = (sv + 1) >> 1;                  // 0,1,1,2,2
        const int kvi = (sv == 0) ? 0 : 2 - (sv & 1);   // 0,1,2,1,2
        const int v0i = sv ? 1 : 0, v1i = sv ? 2 : 0;
        const bool two = (sv > 0);
        const float* Qp  = ws + (size_t)(qvi * 3 + 0) * BHTD + hb;
        const float* Kp  = ws + (size_t)(kvi * 3 + 1) * BHTD + hb;
        const float* V0p = ws + (size_t)(v0i * 3 + 2) * BHTD + hb;
        const float* V1p = ws + (size_t)(v1i * 3 + 2) * BHTD + hb;

        const f4 qa = *(const f4*)&Qp[(size_t)(q0 + r) * 64 + c8];
        const f4 qb = *(const f4*)&Qp[(size_t)(q0 + r) * 64 + c8 + 4];
        __syncthreads();              // prior variant done reading LDS
        *(f4*)&Qs[r][c8]     = qa;
        *(f4*)&Qs[r][c8 + 4] = qb;

        float m_i = NEG_INF, l_i = 0.f;
        float acc0[8], acc1[8];
#pragma unroll
        for (int i = 0; i < 8; i++) { acc0[i] = 0.f; acc1[i] = 0.f; }

        for (int kt = 0; kt <= qtile; ++kt) {
            const int k0 = kt * 32;
            const f4 ka  = *(const f4*)&Kp [(size_t)(k0 + r) * 64 + c8];
            const f4 kb  = *(const f4*)&Kp [(size_t)(k0 + r) * 64 + c8 + 4];
            const f4 va0 = *(const f4*)&V0p[(size_t)(k0 + r) * 64 + c8];
            const f4 vb0 = *(const f4*)&V0p[(size_t)(k0 + r) * 64 + c8 + 4];
            f4 va1 = va0, vb1 = vb0;
            if (two) {
                va1 = *(const f4*)&V1p[(size_t)(k0 + r) * 64 + c8];
                vb1 = *(const f4*)&V1p[(size_t)(k0 + r) * 64 + c8 + 4];
            }
            __syncthreads();          // prior tile done reading Ks/Vs
#pragma unroll
            for (int j = 0; j < 4; j++) {
                Ks[c8 + j][r]     = ka[j];
                Ks[c8 + 4 + j][r] = kb[j];
            }
            *(f4*)&Vs[0][r][c8]     = va0;
            *(f4*)&Vs[0][r][c8 + 4] = vb0;
            if (two) {
                *(f4*)&Vs[1][r][c8]     = va1;
                *(f4*)&Vs[1][r][c8 + 4] = vb1;
            }
            __syncthreads();

            // ---- scores: S[r][c4..c4+3] = Q[r]·K[c] ----
            float s0 = 0.f, s1 = 0.f, s2 = 0.f, s3 = 0.f;
#pragma unroll 4
            for (int d4 = 0; d4 < 16; ++d4) {
                const f4 q4 = *(const f4*)&Qs[r][d4 * 4];
#pragma unroll
                for (int jq = 0; jq < 4; jq++) {
                    const f4 k4 = *(const f4*)&Ks[d4 * 4 + jq][c4];
                    s0 = fmaf(q4[jq], k4[0], s0);
                    s1 = fmaf(q4[jq], k4[1], s1);
                    s2 = fmaf(q4[jq], k4[2], s2);
                    s3 = fmaf(q4[jq], k4[3], s3);
                }
            }
            float s[4] = { s0 * 0.125f, s1 * 0.125f, s2 * 0.125f, s3 * 0.125f };
            if (kt == qtile) {        // diagonal tile: causal mask
                const int qg = q0 + r;
#pragma unroll
                for (int i = 0; i < 4; i++)
                    if (k0 + c4 + i > qg) s[i] = NEG_INF;
            }
            // ---- online softmax (8 lanes per row) ----
            float mx = fmaxf(fmaxf(s[0], s[1]), fmaxf(s[2], s[3]));
            mx = fmaxf(mx, __shfl_xor(mx, 1, 64));
            mx = fmaxf(mx, __shfl_xor(mx, 2, 64));
            mx = fmaxf(mx, __shfl_xor(mx, 4, 64));
            const float newm  = fmaxf(m_i, mx);
            const float alpha = __expf(m_i - newm);
            f4 p;
            float rs = 0.f;
#pragma unroll
            for (int i = 0; i < 4; i++) { p[i] = __expf(s[i] - newm); rs += p[i]; }
            rs += __shfl_xor(rs, 1, 64);
            rs += __shfl_xor(rs, 2, 64);
            rs += __shfl_xor(rs, 4, 64);
            l_i = l_i * alpha + rs;
            m_i = newm;
            *(f4*)&Ps[r][c4] = p;     // row group = same 8 lanes, same wave: no barrier

            // ---- PV accumulate ----
#pragma unroll
            for (int i = 0; i < 8; i++) acc0[i] *= alpha;
            if (two) {
#pragma unroll
                for (int i = 0; i < 8; i++) acc1[i] *= alpha;
            }
#pragma unroll 2
            for (int j4 = 0; j4 < 8; ++j4) {
                const f4 pp = *(const f4*)&Ps[r][j4 * 4];
#pragma unroll
                for (int jj = 0; jj < 4; jj++) {
                    const float pw = pp[jj];
                    const int   jr = j4 * 4 + jj;
                    const f4 v0a = *(const f4*)&Vs[0][jr][c8];
                    const f4 v0b = *(const f4*)&Vs[0][jr][c8 + 4];
#pragma unroll
                    for (int i = 0; i < 4; i++) {
                        acc0[i]     = fmaf(pw, v0a[i], acc0[i]);
                        acc0[4 + i] = fmaf(pw, v0b[i], acc0[4 + i]);
                    }
                    if (two) {
                        const f4 v1a = *(const f4*)&Vs[1][jr][c8];
                        const f4 v1b = *(const f4*)&Vs[1][jr][c8 + 4];
#pragma unroll
                        for (int i = 0; i < 4; i++) {
                            acc1[i]     = fmaf(pw, v1a[i], acc1[i]);
                            acc1[4 + i] = fmaf(pw, v1b[i], acc1[4 + i]);
                        }
                    }
                }
            }
        } // kt

        const float inv = 1.f / l_i;
        if (sv == 0) {
            f4 o0, o1;
#pragma unroll
            for (int i = 0; i < 4; i++) { o0[i] = acc0[i] * inv; o1[i] = acc0[4 + i] * inv; }
            *(f4*)&ybuf[hb + (size_t)(q0 + r) * 64 + c8]     = o0;
            *(f4*)&ybuf[hb + (size_t)(q0 + r) * 64 + c8 + 4] = o1;
        } else if (sv == 1) {
#pragma unroll
            for (int i = 0; i < 8; i++) {
                const float a = acc0[i] * inv, b = acc1[i] * inv;
                olo[i] = fminf(a, b);
                ohi[i] = fmaxf(a, b);
            }
        } else {
#pragma unroll
            for (int i = 0; i < 8; i++) {
                const float a = acc0[i] * inv, b = acc1[i] * inv;
                olo[i] = fminf(olo[i], fminf(a, b));
                ohi[i] = fmaxf(ohi[i], fmaxf(a, b));
            }
        }
    } // sv

    f4 lo0, lo1, hi0, hi1;
#pragma unroll
    for (int i = 0; i < 4; i++) {
        lo0[i] = olo[i]; lo1[i] = olo[4 + i];
        hi0[i] = ohi[i]; hi1[i] = ohi[4 + i];
    }
    *(f4*)&ybuf[(size_t)1 * BHTD + hb + (size_t)(q0 + r) * 64 + c8]     = lo0;
    *(f4*)&ybuf[(size_t)1 * BHTD + hb + (size_t)(q0 + r) * 64 + c8 + 4] = lo1;
    *(f4*)&ybuf[(size_t)2 * BHTD + hb + (size_t)(q0 + r) * 64 + c8]     = hi0;
    *(f4*)&ybuf[(size_t)2 * BHTD + hb + (size_t)(q0 + r) * 64 + c8 + 4] = hi1;
}

// ---------------------------------------------------------------------------
// Kernel 3: output projection out[o] = Y_o @ W_proj^T, Y_o in [B,H,T,D] layout.
// ---------------------------------------------------------------------------
__global__ __launch_bounds__(256) void out_proj(
    const float* __restrict__ ws, const float* __restrict__ Wp,
    float* __restrict__ out)
{
    __shared__ float As[16][68], Bs[16][68];
    const int o  = blockIdx.z;
    const float* Y = ws + (size_t)(9 + o) * BHTD;
    const int j0 = blockIdx.x * 64, n0 = blockIdx.y * 64;
    const int t  = threadIdx.x;
    const int lrow = t >> 2, lf4 = (t & 3) * 4;
    const int tx = t & 15, ty = t >> 4;

    float acc[4][4];
#pragma unroll
    for (int a = 0; a < 4; a++)
#pragma unroll
        for (int b = 0; b < 4; b++) acc[a][b] = 0.f;

    for (int k0 = 0; k0 < NC; k0 += 16) {
        const int n = n0 + lrow;
        const int b = n >> 11, tt2 = n & 2047;
        const int h = k0 >> 6, dd = (k0 & 63) + lf4;   // 16 | 64: slice in one head
        const f4 va = *(const f4*)&Y [((size_t)(b * 12 + h) * NT + tt2) * 64 + dd];
        const f4 vb = *(const f4*)&Wp[(size_t)(j0 + lrow) * NC + k0 + lf4];
        __syncthreads();
#pragma unroll
        for (int q = 0; q < 4; q++) {
            As[lf4 + q][lrow] = va[q];
            Bs[lf4 + q][lrow] = vb[q];
        }
        __syncthreads();
#pragma unroll
        for (int kk = 0; kk < 16; kk++) {
            const f4 a4 = *(const f4*)&As[kk][ty * 4];
            const f4 b4 = *(const f4*)&Bs[kk][tx * 4];
#pragma unroll
            for (int rr = 0; rr < 4; rr++)
#pragma unroll
                for (int cc = 0; cc < 4; cc++)
                    acc[rr][cc] = fmaf(a4[rr], b4[cc], acc[rr][cc]);
        }
    }
#pragma unroll
    for (int rr = 0; rr < 4; rr++) {
        const int n = n0 + ty * 4 + rr;
        f4 fo;
#pragma unroll
        for (int cc = 0; cc < 4; cc++) fo[cc] = acc[rr][cc];
        *(f4*)&out[(size_t)o * BTC + (size_t)n * NC + j0 + tx * 4] = fo;
    }
}

extern "C" void kernel_launch(void* const* d_in, const int* in_sizes, int n_in,
                              void* d_out, int out_size, void* d_ws, size_t ws_size,
                              hipStream_t stream)
{
    const float* x  = (const float*)d_in[0];
    const float* xl = (const float*)d_in[1];
    const float* xu = (const float*)d_in[2];
    const float* Wa = (const float*)d_in[3];
    const float* Wp = (const float*)d_in[4];
    float* out = (float*)d_out;
    float* ws  = (float*)d_ws;   // needs 12*BHTD*4 = 151 MB

    qkv_proj<<<dim3(36, 64), 256, 0, stream>>>(x, xl, xu, Wa, ws);
    flash9  <<<dim3(64, 24), 256, 0, stream>>>(ws);
    out_proj<<<dim3(12, 64, 3), 256, 0, stream>>>(ws, Wp, out);
}

// Round 2
// 2046.883 us; speedup vs baseline: 2.2610x; 2.2610x over previous
//
#include <hip/hip_runtime.h>
#include <hip/hip_bf16.h>
#include <cstdint>

typedef float f4  __attribute__((ext_vector_type(4)));
typedef short s8v __attribute__((ext_vector_type(8)));   // 8 bf16 (4 VGPRs)
typedef short s4v __attribute__((ext_vector_type(4)));

#define BHTD 3145728    // B*H*T*D floats/els = 2*12*2048*64
#define BTC  3145728
#define NT   2048
#define NC   768

__device__ __forceinline__ short bfbits(float f) {
    return __builtin_bit_cast(short, __float2bfloat16(f));
}

template <int ctrl>
__device__ __forceinline__ float dppmov(float x) {
    return __builtin_bit_cast(float,
        __builtin_amdgcn_update_dpp(0, __builtin_bit_cast(int, x), ctrl, 0xF, 0xF, true));
}
// reductions over the 16 lanes of a quad-row (valid: steps 3/4 are mirrors,
// values already uniform within quads after steps 1/2)
__device__ __forceinline__ float red16max(float x) {
    x = fmaxf(x, dppmov<0xB1>(x));    // quad_perm [1,0,3,2]  (xor 1)
    x = fmaxf(x, dppmov<0x4E>(x));    // quad_perm [2,3,0,1]  (xor 2)
    x = fmaxf(x, dppmov<0x141>(x));   // row_half_mirror      (== xor 4 here)
    x = fmaxf(x, dppmov<0x140>(x));   // row_mirror           (== xor 8 here)
    return x;
}
__device__ __forceinline__ float red16sum(float x) {
    x += dppmov<0xB1>(x);
    x += dppmov<0x4E>(x);
    x += dppmov<0x141>(x);
    x += dppmov<0x140>(x);
    return x;
}

// ---------------------------------------------------------------------------
// Kernel 1: fused QKV projection (fp32 compute), bf16 outputs.
//   nom = x@W^T ; mid = m@W^T ; rad = r@|W|^T ; lo=mid-rad ; hi=mid+rad
// qkvb layout: [variant 0..2][part q/k/v][B,H,T,D] bf16 bits (short)
// ---------------------------------------------------------------------------
__global__ __launch_bounds__(256) void qkv_proj(
    const float* __restrict__ x, const float* __restrict__ xl,
    const float* __restrict__ xu, const float* __restrict__ W,
    short* __restrict__ qkvb)
{
    __shared__ float Axs[16][68], Ams[16][68], Ars[16][68], Bws[16][68];
    const int j0 = blockIdx.x * 64;
    const int n0 = blockIdx.y * 64;
    const int t  = threadIdx.x;
    const int lrow = t >> 2;
    const int lf4  = (t & 3) * 4;
    const int tx = t & 15, ty = t >> 4;

    float nom[4][4], mid[4][4], rad[4][4];
#pragma unroll
    for (int a = 0; a < 4; a++)
#pragma unroll
        for (int b = 0; b < 4; b++) { nom[a][b] = 0.f; mid[a][b] = 0.f; rad[a][b] = 0.f; }

    for (int k0 = 0; k0 < NC; k0 += 16) {
        const f4 vx = *(const f4*)&x [(size_t)(n0 + lrow) * NC + k0 + lf4];
        const f4 vl = *(const f4*)&xl[(size_t)(n0 + lrow) * NC + k0 + lf4];
        const f4 vu = *(const f4*)&xu[(size_t)(n0 + lrow) * NC + k0 + lf4];
        const f4 vw = *(const f4*)&W [(size_t)(j0 + lrow) * NC + k0 + lf4];
        __syncthreads();
#pragma unroll
        for (int q = 0; q < 4; q++) {
            Axs[lf4 + q][lrow] = vx[q];
            Ams[lf4 + q][lrow] = 0.5f * (vl[q] + vu[q]);
            Ars[lf4 + q][lrow] = 0.5f * (vu[q] - vl[q]);
            Bws[lf4 + q][lrow] = vw[q];
        }
        __syncthreads();
#pragma unroll
        for (int kk = 0; kk < 16; kk++) {
            const f4 ax = *(const f4*)&Axs[kk][ty * 4];
            const f4 am = *(const f4*)&Ams[kk][ty * 4];
            const f4 ar = *(const f4*)&Ars[kk][ty * 4];
            const f4 bw = *(const f4*)&Bws[kk][tx * 4];
#pragma unroll
            for (int rr = 0; rr < 4; rr++)
#pragma unroll
                for (int cc = 0; cc < 4; cc++) {
                    nom[rr][cc] = fmaf(ax[rr], bw[cc], nom[rr][cc]);
                    mid[rr][cc] = fmaf(am[rr], bw[cc], mid[rr][cc]);
                    rad[rr][cc] = fmaf(ar[rr], fabsf(bw[cc]), rad[rr][cc]);
                }
        }
    }
    const int p = j0 / NC;
    const int h = (j0 % NC) / 64;
    const int d = tx * 4;
#pragma unroll
    for (int rr = 0; rr < 4; rr++) {
        const int n  = n0 + ty * 4 + rr;
        const int b  = n >> 11, tt2 = n & 2047;
        const size_t base = ((size_t)(b * 12 + h) * NT + tt2) * 64 + d;
        s4v vn, vlo, vhi;
#pragma unroll
        for (int cc = 0; cc < 4; cc++) {
            vn[cc]  = bfbits(nom[rr][cc]);
            vlo[cc] = bfbits(mid[rr][cc] - rad[rr][cc]);
            vhi[cc] = bfbits(mid[rr][cc] + rad[rr][cc]);
        }
        *(s4v*)&qkvb[(size_t)(0 * 3 + p) * BHTD + base] = vn;
        *(s4v*)&qkvb[(size_t)(1 * 3 + p) * BHTD + base] = vlo;
        *(s4v*)&qkvb[(size_t)(2 * 3 + p) * BHTD + base] = vhi;
    }
}

// ---------------------------------------------------------------------------
// Kernel 2: MFMA flash attention, 5 score-variant passes:
//   sv0: (qn,kn)x{vn} -> y ; sv1..4: (q lo/hi, k lo/hi)x{vlo,vhi} -> min/max
// Block = 64 q-rows (4 waves x 16 rows), K-tile = 32.
// mfma_f32_16x16x32_bf16 layouts:
//   A[m=lane&15][k=quad*8+j], B[k=quad*8+j][n=lane&15], C/D col=lane&15,row=quad*4+reg
// ---------------------------------------------------------------------------
__global__ __launch_bounds__(256) void flash_mfma(
    const short* __restrict__ qkvb, float* __restrict__ ybuf)
{
    const int qt  = (int)gridDim.x - 1 - (int)blockIdx.x;   // heavy first
    const int bh  = blockIdx.y;
    const int q0  = qt * 64;
    const int t   = threadIdx.x;
    const int wave = t >> 6, lane = t & 63;
    const int quad = lane >> 4, l16 = lane & 15;
    const int rowb = q0 + 16 * wave;

    __shared__ short Ks[32][72];       // row-major K-tile  (stride 144B -> 2-way)
    __shared__ short Vt[2][64][40];    // transposed V-tile Vt[d][k] (stride 80B -> 2-way)
    __shared__ short Ps[64][40];       // P row-major, A-layout reads

    const size_t hb = (size_t)bh * (NT * 64);

    f4 olo[4], ohi[4];
#pragma unroll
    for (int i = 0; i < 4; i++) { olo[i] = f4{0,0,0,0}; ohi[i] = f4{0,0,0,0}; }

    for (int sv = 0; sv < 5; ++sv) {
        const int qvi = (sv + 1) >> 1;
        const int kvi = (sv == 0) ? 0 : 2 - (sv & 1);
        const int v0i = sv ? 1 : 0, v1i = sv ? 2 : 0;
        const bool two = (sv > 0);
        const short* Qp  = qkvb + (size_t)(qvi * 3 + 0) * BHTD + hb;
        const short* Kp  = qkvb + (size_t)(kvi * 3 + 1) * BHTD + hb;
        const short* V0p = qkvb + (size_t)(v0i * 3 + 2) * BHTD + hb;
        const short* V1p = qkvb + (size_t)(v1i * 3 + 2) * BHTD + hb;

        const size_t qoff = (size_t)(rowb + l16) * 64 + quad * 8;
        const s8v qf0 = *(const s8v*)&Qp[qoff];
        const s8v qf1 = *(const s8v*)&Qp[qoff + 32];

        float mi[4], li[4];
        f4 acc0[4], acc1[4];
#pragma unroll
        for (int r = 0; r < 4; r++) { mi[r] = -1e30f; li[r] = 0.f; }
#pragma unroll
        for (int i = 0; i < 4; i++) { acc0[i] = f4{0,0,0,0}; acc1[i] = f4{0,0,0,0}; }

        const int ktn = 2 * qt + 2;
        for (int kt = 0; kt < ktn; ++kt) {
            const int k0 = kt * 32;
            __syncthreads();           // prior iter's LDS reads complete
            {
                const int kr = t >> 3, d0 = (t & 7) * 8;
                const size_t goff = (size_t)(k0 + kr) * 64 + d0;
                const s8v kv = *(const s8v*)&Kp[goff];
                const s8v v0 = *(const s8v*)&V0p[goff];
                *(s8v*)&Ks[kr][d0] = kv;
#pragma unroll
                for (int j = 0; j < 8; j++) Vt[0][d0 + j][kr] = v0[j];
                if (two) {
                    const s8v v1 = *(const s8v*)&V1p[goff];
#pragma unroll
                    for (int j = 0; j < 8; j++) Vt[1][d0 + j][kr] = v1[j];
                }
            }
            __syncthreads();

            // ---- S = Q K^T : two 16x16 col-tiles, K-dim 64 in 2 chunks ----
            f4 s0 = f4{0,0,0,0}, s1 = f4{0,0,0,0};
            {
                s8v kf;
                kf = *(const s8v*)&Ks[l16][quad * 8];
                s0 = __builtin_amdgcn_mfma_f32_16x16x32_bf16(qf0, kf, s0, 0, 0, 0);
                kf = *(const s8v*)&Ks[l16][32 + quad * 8];
                s0 = __builtin_amdgcn_mfma_f32_16x16x32_bf16(qf1, kf, s0, 0, 0, 0);
                kf = *(const s8v*)&Ks[16 + l16][quad * 8];
                s1 = __builtin_amdgcn_mfma_f32_16x16x32_bf16(qf0, kf, s1, 0, 0, 0);
                kf = *(const s8v*)&Ks[16 + l16][32 + quad * 8];
                s1 = __builtin_amdgcn_mfma_f32_16x16x32_bf16(qf1, kf, s1, 0, 0, 0);
            }
            float a0[4], a1[4];
#pragma unroll
            for (int r = 0; r < 4; r++) { a0[r] = s0[r] * 0.125f; a1[r] = s1[r] * 0.125f; }
            if (k0 + 31 > rowb) {      // causal mask (only near-diagonal tiles)
#pragma unroll
                for (int r = 0; r < 4; r++) {
                    const int row = rowb + quad * 4 + r;
                    if (k0 + l16 > row)      a0[r] = -1e30f;
                    if (k0 + 16 + l16 > row) a1[r] = -1e30f;
                }
            }
            // ---- online softmax (row = quad*4+r, 16 lanes/row) ----
            float al[4], rs[4];
#pragma unroll
            for (int r = 0; r < 4; r++) {
                float mx = red16max(fmaxf(a0[r], a1[r]));
                const float nm = fmaxf(mi[r], mx);
                al[r] = __expf(mi[r] - nm);
                a0[r] = __expf(a0[r] - nm);
                a1[r] = __expf(a1[r] - nm);
                mi[r] = nm;
                rs[r] = a0[r] + a1[r];
            }
#pragma unroll
            for (int r = 0; r < 4; r++) { rs[r] = red16sum(rs[r]); li[r] = li[r] * al[r] + rs[r]; }
            // P -> LDS (wave-private rows; no barrier needed)
#pragma unroll
            for (int r = 0; r < 4; r++) {
                Ps[16 * wave + quad * 4 + r][l16]      = bfbits(a0[r]);
                Ps[16 * wave + quad * 4 + r][16 + l16] = bfbits(a1[r]);
            }
            // rescale accumulators
#pragma unroll
            for (int dt = 0; dt < 4; dt++)
#pragma unroll
                for (int r = 0; r < 4; r++) acc0[dt][r] *= al[r];
            if (two) {
#pragma unroll
                for (int dt = 0; dt < 4; dt++)
#pragma unroll
                    for (int r = 0; r < 4; r++) acc1[dt][r] *= al[r];
            }
            // ---- O += P V : 4 d-tiles, K-dim exactly 32 ----
            const s8v pf = *(const s8v*)&Ps[16 * wave + l16][quad * 8];
#pragma unroll
            for (int dt = 0; dt < 4; ++dt) {
                s8v vf = *(const s8v*)&Vt[0][16 * dt + l16][quad * 8];
                acc0[dt] = __builtin_amdgcn_mfma_f32_16x16x32_bf16(pf, vf, acc0[dt], 0, 0, 0);
                if (two) {
                    vf = *(const s8v*)&Vt[1][16 * dt + l16][quad * 8];
                    acc1[dt] = __builtin_amdgcn_mfma_f32_16x16x32_bf16(pf, vf, acc1[dt], 0, 0, 0);
                }
            }
        } // kt

        float inv[4];
#pragma unroll
        for (int r = 0; r < 4; r++) inv[r] = 1.f / li[r];
        if (sv == 0) {
#pragma unroll
            for (int dt = 0; dt < 4; dt++)
#pragma unroll
                for (int r = 0; r < 4; r++)
                    ybuf[hb + (size_t)(rowb + quad * 4 + r) * 64 + dt * 16 + l16] =
                        acc0[dt][r] * inv[r];
        } else if (sv == 1) {
#pragma unroll
            for (int dt = 0; dt < 4; dt++)
#pragma unroll
                for (int r = 0; r < 4; r++) {
                    const float xa = acc0[dt][r] * inv[r], xb = acc1[dt][r] * inv[r];
                    olo[dt][r] = fminf(xa, xb);
                    ohi[dt][r] = fmaxf(xa, xb);
                }
        } else {
#pragma unroll
            for (int dt = 0; dt < 4; dt++)
#pragma unroll
                for (int r = 0; r < 4; r++) {
                    const float xa = acc0[dt][r] * inv[r], xb = acc1[dt][r] * inv[r];
                    olo[dt][r] = fminf(olo[dt][r], fminf(xa, xb));
                    ohi[dt][r] = fmaxf(ohi[dt][r], fmaxf(xa, xb));
                }
        }
    } // sv

    float* ylo = ybuf + (size_t)BHTD;
    float* yhi = ybuf + (size_t)2 * BHTD;
#pragma unroll
    for (int dt = 0; dt < 4; dt++)
#pragma unroll
        for (int r = 0; r < 4; r++) {
            const size_t o = hb + (size_t)(rowb + quad * 4 + r) * 64 + dt * 16 + l16;
            ylo[o] = olo[dt][r];
            yhi[o] = ohi[dt][r];
        }
}

// ---------------------------------------------------------------------------
// Kernel 3: output projection out[o] = Y_o @ W_proj^T (fp32)
// ---------------------------------------------------------------------------
__global__ __launch_bounds__(256) void out_proj(
    const float* __restrict__ ybuf, const float* __restrict__ Wp,
    float* __restrict__ out)
{
    __shared__ float As[16][68], Bs[16][68];
    const int o  = blockIdx.z;
    const float* Y = ybuf + (size_t)o * BHTD;
    const int j0 = blockIdx.x * 64, n0 = blockIdx.y * 64;
    const int t  = threadIdx.x;
    const int lrow = t >> 2, lf4 = (t & 3) * 4;
    const int tx = t & 15, ty = t >> 4;

    float acc[4][4];
#pragma unroll
    for (int a = 0; a < 4; a++)
#pragma unroll
        for (int b = 0; b < 4; b++) acc[a][b] = 0.f;

    for (int k0 = 0; k0 < NC; k0 += 16) {
        const int n = n0 + lrow;
        const int b = n >> 11, tt2 = n & 2047;
        const int h = k0 >> 6, dd = (k0 & 63) + lf4;
        const f4 va = *(const f4*)&Y [((size_t)(b * 12 + h) * NT + tt2) * 64 + dd];
        const f4 vb = *(const f4*)&Wp[(size_t)(j0 + lrow) * NC + k0 + lf4];
        __syncthreads();
#pragma unroll
        for (int q = 0; q < 4; q++) {
            As[lf4 + q][lrow] = va[q];
            Bs[lf4 + q][lrow] = vb[q];
        }
        __syncthreads();
#pragma unroll
        for (int kk = 0; kk < 16; kk++) {
            const f4 a4 = *(const f4*)&As[kk][ty * 4];
            const f4 b4 = *(const f4*)&Bs[kk][tx * 4];
#pragma unroll
            for (int rr = 0; rr < 4; rr++)
#pragma unroll
                for (int cc = 0; cc < 4; cc++)
                    acc[rr][cc] = fmaf(a4[rr], b4[cc], acc[rr][cc]);
        }
    }
#pragma unroll
    for (int rr = 0; rr < 4; rr++) {
        const int n = n0 + ty * 4 + rr;
        f4 fo;
#pragma unroll
        for (int cc = 0; cc < 4; cc++) fo[cc] = acc[rr][cc];
        *(f4*)&out[(size_t)o * BTC + (size_t)n * NC + j0 + tx * 4] = fo;
    }
}

extern "C" void kernel_launch(void* const* d_in, const int* in_sizes, int n_in,
                              void* d_out, int out_size, void* d_ws, size_t ws_size,
                              hipStream_t stream)
{
    const float* x  = (const float*)d_in[0];
    const float* xl = (const float*)d_in[1];
    const float* xu = (const float*)d_in[2];
    const float* Wa = (const float*)d_in[3];
    const float* Wp = (const float*)d_in[4];
    float* out = (float*)d_out;

    short* qkvb = (short*)d_ws;                                       // 9*BHTD bf16 = 56.6 MB
    float* ybuf = (float*)((char*)d_ws + (size_t)9 * BHTD * 2);       // 3*BHTD f32 = 37.7 MB

    qkv_proj  <<<dim3(36, 64),    256, 0, stream>>>(x, xl, xu, Wa, qkvb);
    flash_mfma<<<dim3(32, 24),    256, 0, stream>>>(qkvb, ybuf);
    out_proj  <<<dim3(12, 64, 3), 256, 0, stream>>>(ybuf, Wp, out);
}

// Round 3
// 867.925 us; speedup vs baseline: 5.3322x; 2.3584x over previous
//
#include <hip/hip_runtime.h>
#include <hip/hip_bf16.h>
#include <cstdint>

typedef float f4  __attribute__((ext_vector_type(4)));
typedef short s8v __attribute__((ext_vector_type(8)));   // 8 bf16 (4 VGPRs)
typedef int   i4v __attribute__((ext_vector_type(4)));

#define BHTD 3145728    // B*H*T*D = 2*12*2048*64
#define BTC  3145728
#define NT   2048
#define NC   768
#define NEG  -1e30f

static __device__ __forceinline__ short bfbits(float f) {
    return __builtin_bit_cast(short, __float2bfloat16(f));
}
static __device__ __forceinline__ float bf2f(short s) {
    return __builtin_bit_cast(float, (int)(((unsigned int)(unsigned short)s) << 16));
}
template <int ctrl>
static __device__ __forceinline__ float dppmov(float x) {
    return __builtin_bit_cast(float,
        __builtin_amdgcn_update_dpp(0, __builtin_bit_cast(int, x), ctrl, 0xF, 0xF, true));
}
// reductions over the 16 lanes of a quad (DPP row = 16 lanes)
static __device__ __forceinline__ float red16max(float x) {
    x = fmaxf(x, dppmov<0xB1>(x));    // quad_perm xor1
    x = fmaxf(x, dppmov<0x4E>(x));    // quad_perm xor2
    x = fmaxf(x, dppmov<0x141>(x));   // row_half_mirror (xor4)
    x = fmaxf(x, dppmov<0x140>(x));   // row_mirror      (xor8)
    return x;
}
static __device__ __forceinline__ float red16sum(float x) {
    x += dppmov<0xB1>(x);
    x += dppmov<0x4E>(x);
    x += dppmov<0x141>(x);
    x += dppmov<0x140>(x);
    return x;
}

// ---------------------------------------------------------------------------
// Kernel 1: MFMA QKV projection. nom=x@W^T, mid=m@W^T, rad=r@|W|^T (bf16 in,
// fp32 acc). Outputs bf16: Q,K in [var][part][B,H,T,D]; V in [B,H,D,T]
// (transposed at producer so flash needs no LDS transpose).
// Block: 64(M)x64(N), 4 waves (16 M-rows each), K-step 32.
// ---------------------------------------------------------------------------
__global__ __launch_bounds__(256) void qkv_proj_mfma(
    const float* __restrict__ x, const float* __restrict__ xl,
    const float* __restrict__ xu, const float* __restrict__ W,
    short* __restrict__ qkvb)
{
    __shared__ short sm[4 * 64 * 40];   // 20 KB staging; epilogue reuses as [64][72]
    short* Ax = sm;
    short* Am = sm + 2560;
    short* Ar = sm + 5120;
    short* Bw = sm + 7680;
    short* Eb = sm;                     // epilogue [64][72] (4608 shorts)

    const int j0 = blockIdx.x * 64;     // N in [0,2304)
    const int n0 = blockIdx.y * 64;     // M in [0,4096)
    const int t  = threadIdx.x;
    const int wv = t >> 6, lane = t & 63, quad = lane >> 4, l16 = lane & 15;
    const int rw = t >> 2, koff = (t & 3) * 8;

    f4 aN[4], aM[4], aR[4];
#pragma unroll
    for (int i = 0; i < 4; i++) { aN[i] = f4{0,0,0,0}; aM[i] = f4{0,0,0,0}; aR[i] = f4{0,0,0,0}; }

    for (int k0 = 0; k0 < NC; k0 += 32) {
        const size_t xo = (size_t)(n0 + rw) * NC + k0 + koff;
        const f4 x0 = *(const f4*)&x[xo],  x1 = *(const f4*)&x[xo + 4];
        const f4 l0 = *(const f4*)&xl[xo], l1 = *(const f4*)&xl[xo + 4];
        const f4 u0 = *(const f4*)&xu[xo], u1 = *(const f4*)&xu[xo + 4];
        const size_t wo = (size_t)(j0 + rw) * NC + k0 + koff;
        const f4 w0 = *(const f4*)&W[wo], w1 = *(const f4*)&W[wo + 4];
        s8v vx, vm, vr, vw;
#pragma unroll
        for (int i = 0; i < 4; i++) {
            vx[i]     = bfbits(x0[i]);              vx[4 + i] = bfbits(x1[i]);
            vm[i]     = bfbits(0.5f * (l0[i] + u0[i])); vm[4 + i] = bfbits(0.5f * (l1[i] + u1[i]));
            vr[i]     = bfbits(0.5f * (u0[i] - l0[i])); vr[4 + i] = bfbits(0.5f * (u1[i] - l1[i]));
            vw[i]     = bfbits(w0[i]);              vw[4 + i] = bfbits(w1[i]);
        }
        __syncthreads();
        *(s8v*)&Ax[rw * 40 + koff] = vx;
        *(s8v*)&Am[rw * 40 + koff] = vm;
        *(s8v*)&Ar[rw * 40 + koff] = vr;
        *(s8v*)&Bw[rw * 40 + koff] = vw;
        __syncthreads();
        const s8v fx = *(const s8v*)&Ax[(wv * 16 + l16) * 40 + quad * 8];
        const s8v fm = *(const s8v*)&Am[(wv * 16 + l16) * 40 + quad * 8];
        const s8v fr = *(const s8v*)&Ar[(wv * 16 + l16) * 40 + quad * 8];
#pragma unroll
        for (int nt = 0; nt < 4; ++nt) {
            const s8v fb = *(const s8v*)&Bw[(nt * 16 + l16) * 40 + quad * 8];
            i4v bi = __builtin_bit_cast(i4v, fb);
#pragma unroll
            for (int i = 0; i < 4; i++) bi[i] &= 0x7fff7fff;
            const s8v fa = __builtin_bit_cast(s8v, bi);
            aN[nt] = __builtin_amdgcn_mfma_f32_16x16x32_bf16(fx, fb, aN[nt], 0, 0, 0);
            aM[nt] = __builtin_amdgcn_mfma_f32_16x16x32_bf16(fm, fb, aM[nt], 0, 0, 0);
            aR[nt] = __builtin_amdgcn_mfma_f32_16x16x32_bf16(fr, fa, aR[nt], 0, 0, 0);
        }
    }

    const int p = j0 / NC, hh = (j0 % NC) >> 6;
    const int cc16 = (t & 3) * 16;
    for (int var = 0; var < 3; ++var) {
        __syncthreads();
#pragma unroll
        for (int nt = 0; nt < 4; ++nt)
#pragma unroll
            for (int r = 0; r < 4; ++r) {
                const float v = (var == 0) ? aN[nt][r]
                              : (var == 1) ? aM[nt][r] - aR[nt][r]
                                           : aM[nt][r] + aR[nt][r];
                Eb[(wv * 16 + quad * 4 + r) * 72 + nt * 16 + l16] = bfbits(v);
            }
        __syncthreads();
        short* dst = qkvb + (size_t)(var * 3 + p) * BHTD;
        if (p < 2) {       // Q,K row-major [B,H,T,D]
            const int token = n0 + rw, b = token >> 11, tt = token & 2047;
            const size_t o = ((size_t)(b * 12 + hh) * NT + tt) * 64 + cc16;
            *(s8v*)&dst[o]     = *(const s8v*)&Eb[rw * 72 + cc16];
            *(s8v*)&dst[o + 8] = *(const s8v*)&Eb[rw * 72 + cc16 + 8];
        } else {           // V transposed [B,H,D,T]
            const int d = rw;
            s8v e0, e1;
#pragma unroll
            for (int i = 0; i < 8; i++) e0[i] = Eb[(cc16 + i) * 72 + d];
#pragma unroll
            for (int i = 0; i < 8; i++) e1[i] = Eb[(cc16 + 8 + i) * 72 + d];
            const int token0 = n0 + cc16, b = token0 >> 11, tt = token0 & 2047;
            const size_t o = ((size_t)(b * 12 + hh) * 64 + d) * NT + tt;
            *(s8v*)&dst[o]     = e0;
            *(s8v*)&dst[o + 8] = e1;
        }
    }
}

// ---------------------------------------------------------------------------
// Kernel 2: MFMA flash, ONE sv per block (sv split across grid.z).
//   TWO=false: sv0 (qn,kn,vn) -> y fp32
//   TWO=true : sv=1+z in 1..4: (q lo/hi, k lo/hi) x {vlo,vhi} -> candLo/candHi bf16
// Block = 128 q-rows, 4 waves x 32 rows (2 m-tiles), K-tile 32.
// ---------------------------------------------------------------------------
template <bool TWO>
__global__ __launch_bounds__(256) void flash_mfma(
    const short* __restrict__ qkvb, float* __restrict__ ybuf,
    short* __restrict__ cand)
{
    const int qt = 15 - (int)blockIdx.x;   // heavy first
    const int bh = blockIdx.y;
    const int q0 = qt * 128;
    const int t  = threadIdx.x;
    const int wv = t >> 6, lane = t & 63, quad = lane >> 4, l16 = lane & 15;

    __shared__ short Ks[32 * 72];          // [kpos][d] pad->2-way
    __shared__ short Vs[2][64 * 40];       // [d][kpos] pad->2-way (from global V^T)
    __shared__ short Ps[128 * 40];         // [qrow][kpos]

    int sv, qvi, kvi, v0i, v1i;
    if (TWO) { sv = 1 + (int)blockIdx.z; qvi = (sv + 1) >> 1; kvi = 2 - (sv & 1); v0i = 1; v1i = 2; }
    else     { sv = 0; qvi = 0; kvi = 0; v0i = 0; v1i = 0; }

    const size_t hb = (size_t)bh * (NT * 64);
    const short* Qp  = qkvb + (size_t)(qvi * 3 + 0) * BHTD + hb;  // [t][d]
    const short* Kp  = qkvb + (size_t)(kvi * 3 + 1) * BHTD + hb;  // [t][d]
    const short* V0p = qkvb + (size_t)(v0i * 3 + 2) * BHTD + hb;  // [d][t] !
    const short* V1p = qkvb + (size_t)(v1i * 3 + 2) * BHTD + hb;

    s8v qf[2][2];
#pragma unroll
    for (int mt = 0; mt < 2; ++mt)
#pragma unroll
        for (int ch = 0; ch < 2; ++ch)
            qf[mt][ch] = *(const s8v*)&Qp[(size_t)(q0 + 32 * wv + 16 * mt + l16) * 64 + ch * 32 + quad * 8];

    float mi[2][4], li[2][4];
    f4 acc0[2][4], acc1[2][4];
#pragma unroll
    for (int mt = 0; mt < 2; ++mt)
#pragma unroll
        for (int r = 0; r < 4; ++r) { mi[mt][r] = NEG; li[mt][r] = 0.f; }
#pragma unroll
    for (int mt = 0; mt < 2; ++mt)
#pragma unroll
        for (int i = 0; i < 4; ++i) { acc0[mt][i] = f4{0,0,0,0}; acc1[mt][i] = f4{0,0,0,0}; }

    const int ktn  = 4 * qt + 4;
    const int mykt = 4 * qt + wv + 1;      // last tile this wave's rows need
    const int skr = t >> 3, skc = (t & 7) * 8;   // K stage: 32 x 64
    const int svd = t >> 2, svc = (t & 3) * 8;   // V stage: 64 x 32

    for (int kt = 0; kt < ktn; ++kt) {
        const int k0 = kt * 32;
        __syncthreads();
        *(s8v*)&Ks[skr * 72 + skc]    = *(const s8v*)&Kp[(size_t)(k0 + skr) * 64 + skc];
        *(s8v*)&Vs[0][svd * 40 + svc] = *(const s8v*)&V0p[(size_t)svd * NT + k0 + svc];
        if (TWO)
            *(s8v*)&Vs[1][svd * 40 + svc] = *(const s8v*)&V1p[(size_t)svd * NT + k0 + svc];
        __syncthreads();
        if (kt >= mykt) continue;          // fully-masked for this wave (barrier already done)

        // ---- S = Q K^T ----
        f4 s[2][2];
#pragma unroll
        for (int mt = 0; mt < 2; ++mt) { s[mt][0] = f4{0,0,0,0}; s[mt][1] = f4{0,0,0,0}; }
#pragma unroll
        for (int nt = 0; nt < 2; ++nt)
#pragma unroll
            for (int ch = 0; ch < 2; ++ch) {
                const s8v kf = *(const s8v*)&Ks[(nt * 16 + l16) * 72 + ch * 32 + quad * 8];
                s[0][nt] = __builtin_amdgcn_mfma_f32_16x16x32_bf16(qf[0][ch], kf, s[0][nt], 0, 0, 0);
                s[1][nt] = __builtin_amdgcn_mfma_f32_16x16x32_bf16(qf[1][ch], kf, s[1][nt], 0, 0, 0);
            }

        // ---- softmax per m-tile ----
#pragma unroll
        for (int mt = 0; mt < 2; ++mt) {
            const int rowb = q0 + 32 * wv + 16 * mt;
            float a0[4], a1[4];
#pragma unroll
            for (int r = 0; r < 4; ++r) { a0[r] = s[mt][0][r] * 0.125f; a1[r] = s[mt][1][r] * 0.125f; }
            if (k0 + 31 > rowb) {
#pragma unroll
                for (int r = 0; r < 4; ++r) {
                    const int row = rowb + quad * 4 + r;
                    if (k0 + l16 > row)      a0[r] = NEG;
                    if (k0 + 16 + l16 > row) a1[r] = NEG;
                }
            }
#pragma unroll
            for (int r = 0; r < 4; ++r) {
                const float mx = red16max(fmaxf(a0[r], a1[r]));
                const float nm = fmaxf(mi[mt][r], mx);
                const float al = __expf(mi[mt][r] - nm);
                a0[r] = __expf(a0[r] - nm);
                a1[r] = __expf(a1[r] - nm);
                mi[mt][r] = nm;
                const float rs = red16sum(a0[r] + a1[r]);
                li[mt][r] = li[mt][r] * al + rs;
                Ps[(32 * wv + 16 * mt + quad * 4 + r) * 40 + l16]      = bfbits(a0[r]);
                Ps[(32 * wv + 16 * mt + quad * 4 + r) * 40 + 16 + l16] = bfbits(a1[r]);
#pragma unroll
                for (int dt = 0; dt < 4; ++dt) acc0[mt][dt][r] *= al;
                if (TWO) {
#pragma unroll
                    for (int dt = 0; dt < 4; ++dt) acc1[mt][dt][r] *= al;
                }
            }
        }
        // ---- O += P V ----
        const s8v pf0 = *(const s8v*)&Ps[(32 * wv + l16) * 40 + quad * 8];
        const s8v pf1 = *(const s8v*)&Ps[(32 * wv + 16 + l16) * 40 + quad * 8];
#pragma unroll
        for (int dt = 0; dt < 4; ++dt) {
            const s8v vf0 = *(const s8v*)&Vs[0][(dt * 16 + l16) * 40 + quad * 8];
            acc0[0][dt] = __builtin_amdgcn_mfma_f32_16x16x32_bf16(pf0, vf0, acc0[0][dt], 0, 0, 0);
            acc0[1][dt] = __builtin_amdgcn_mfma_f32_16x16x32_bf16(pf1, vf0, acc0[1][dt], 0, 0, 0);
            if (TWO) {
                const s8v vf1 = *(const s8v*)&Vs[1][(dt * 16 + l16) * 40 + quad * 8];
                acc1[0][dt] = __builtin_amdgcn_mfma_f32_16x16x32_bf16(pf0, vf1, acc1[0][dt], 0, 0, 0);
                acc1[1][dt] = __builtin_amdgcn_mfma_f32_16x16x32_bf16(pf1, vf1, acc1[1][dt], 0, 0, 0);
            }
        }
    }

#pragma unroll
    for (int mt = 0; mt < 2; ++mt) {
        float inv[4];
#pragma unroll
        for (int r = 0; r < 4; ++r) inv[r] = 1.f / li[mt][r];
#pragma unroll
        for (int dt = 0; dt < 4; ++dt)
#pragma unroll
            for (int r = 0; r < 4; ++r) {
                const size_t o = hb + (size_t)(q0 + 32 * wv + 16 * mt + quad * 4 + r) * 64 + dt * 16 + l16;
                if (!TWO) {
                    ybuf[o] = acc0[mt][dt][r] * inv[r];
                } else {
                    const float xa = acc0[mt][dt][r] * inv[r];
                    const float xb = acc1[mt][dt][r] * inv[r];
                    cand[(size_t)(sv - 1) * BHTD + o] = bfbits(fminf(xa, xb));
                    cand[(size_t)(3 + sv) * BHTD + o] = bfbits(fmaxf(xa, xb));
                }
            }
    }
}

// ---------------------------------------------------------------------------
// Kernel 3: MFMA output projection. z=0: A=y fp32; z=1: A=min of 4 candLo;
// z=2: A=max of 4 candHi. B=Wp (bf16). out fp32 via LDS re-layout.
// ---------------------------------------------------------------------------
__global__ __launch_bounds__(256) void out_proj_mfma(
    const float* __restrict__ ybuf, const short* __restrict__ cand,
    const float* __restrict__ Wp, float* __restrict__ out)
{
    __shared__ float smf[64 * 68];          // 17.4 KB; staging aliases first 10.2 KB
    short* As = (short*)smf;                // [64][40]
    short* Bs = As + 2560;
    float* Eb = smf;                        // [64][68]

    const int o  = blockIdx.z;
    const int j0 = blockIdx.x * 64, n0 = blockIdx.y * 64;
    const int t  = threadIdx.x;
    const int wv = t >> 6, lane = t & 63, quad = lane >> 4, l16 = lane & 15;
    const int rw = t >> 2, koff = (t & 3) * 8;

    f4 acc[4];
#pragma unroll
    for (int i = 0; i < 4; i++) acc[i] = f4{0,0,0,0};

    const int token = n0 + rw, b = token >> 11, tt = token & 2047;

    for (int k0 = 0; k0 < NC; k0 += 32) {
        const int hh = k0 >> 6, d0 = (k0 & 63) + koff;
        const size_t aoff = ((size_t)(b * 12 + hh) * NT + tt) * 64 + d0;
        s8v av;
        if (o == 0) {
            const f4 y0 = *(const f4*)&ybuf[aoff];
            const f4 y1 = *(const f4*)&ybuf[aoff + 4];
#pragma unroll
            for (int i = 0; i < 4; i++) { av[i] = bfbits(y0[i]); av[4 + i] = bfbits(y1[i]); }
        } else {
            const short* cb = cand + (size_t)(o == 1 ? 0 : 4) * BHTD;
            float v[8];
            {
                const s8v c0 = *(const s8v*)&cb[aoff];
#pragma unroll
                for (int i = 0; i < 8; i++) v[i] = bf2f(c0[i]);
            }
#pragma unroll
            for (int q = 1; q < 4; ++q) {
                const s8v cq = *(const s8v*)&cb[(size_t)q * BHTD + aoff];
                if (o == 1) {
#pragma unroll
                    for (int i = 0; i < 8; i++) v[i] = fminf(v[i], bf2f(cq[i]));
                } else {
#pragma unroll
                    for (int i = 0; i < 8; i++) v[i] = fmaxf(v[i], bf2f(cq[i]));
                }
            }
#pragma unroll
            for (int i = 0; i < 8; i++) av[i] = bfbits(v[i]);
        }
        const size_t wo = (size_t)(j0 + rw) * NC + k0 + koff;
        const f4 w0 = *(const f4*)&Wp[wo], w1 = *(const f4*)&Wp[wo + 4];
        s8v bv;
#pragma unroll
        for (int i = 0; i < 4; i++) { bv[i] = bfbits(w0[i]); bv[4 + i] = bfbits(w1[i]); }
        __syncthreads();
        *(s8v*)&As[rw * 40 + koff] = av;
        *(s8v*)&Bs[rw * 40 + koff] = bv;
        __syncthreads();
        const s8v af = *(const s8v*)&As[(wv * 16 + l16) * 40 + quad * 8];
#pragma unroll
        for (int nt = 0; nt < 4; ++nt) {
            const s8v bf = *(const s8v*)&Bs[(nt * 16 + l16) * 40 + quad * 8];
            acc[nt] = __builtin_amdgcn_mfma_f32_16x16x32_bf16(af, bf, acc[nt], 0, 0, 0);
        }
    }
    __syncthreads();
#pragma unroll
    for (int nt = 0; nt < 4; ++nt)
#pragma unroll
        for (int r = 0; r < 4; ++r)
            Eb[(wv * 16 + quad * 4 + r) * 68 + nt * 16 + l16] = acc[nt][r];
    __syncthreads();
    const int cc = (t & 3) * 16;
#pragma unroll
    for (int i = 0; i < 4; ++i) {
        const f4 vo = *(const f4*)&Eb[rw * 68 + cc + 4 * i];
        *(f4*)&out[(size_t)o * BTC + (size_t)(n0 + rw) * NC + j0 + cc + 4 * i] = vo;
    }
}

extern "C" void kernel_launch(void* const* d_in, const int* in_sizes, int n_in,
                              void* d_out, int out_size, void* d_ws, size_t ws_size,
                              hipStream_t stream)
{
    const float* x  = (const float*)d_in[0];
    const float* xl = (const float*)d_in[1];
    const float* xu = (const float*)d_in[2];
    const float* Wa = (const float*)d_in[3];
    const float* Wp = (const float*)d_in[4];
    float* out = (float*)d_out;

    short* qkvb = (short*)d_ws;                       // 9*BHTD bf16  = 56.6 MB
    float* ybuf = (float*)(qkvb + (size_t)9 * BHTD);  // 1*BHTD f32   = 12.6 MB
    short* cand = (short*)(ybuf + (size_t)BHTD);      // 8*BHTD bf16  = 50.3 MB

    qkv_proj_mfma   <<<dim3(36, 64),    256, 0, stream>>>(x, xl, xu, Wa, qkvb);
    flash_mfma<false><<<dim3(16, 24),    256, 0, stream>>>(qkvb, ybuf, nullptr);
    flash_mfma<true> <<<dim3(16, 24, 4), 256, 0, stream>>>(qkvb, ybuf, cand);
    out_proj_mfma   <<<dim3(12, 64, 3), 256, 0, stream>>>(ybuf, cand, Wp, out);
}